// Round 3
// baseline (343.937 us; speedup 1.0000x reference)
//
#include <hip/hip_runtime.h>

#define TT    512
#define WW    257
#define HWSZ  (WW*WW)          // 66049
#define IMG2  (2*HWSZ)         // time stride in `output` (2 channels)
#define PX    65280            // 255 rows * 256 padded cols (interior, col 255 = pad)
#define SCALE 3.5682482323055424f   // DT^-0.5 / gamma(1.5)
#define KD    163.84f               // KAPPA / DX^2

typedef short bf16x8 __attribute__((ext_vector_type(8)));
typedef short bf16x4 __attribute__((ext_vector_type(4)));
typedef float f32x4  __attribute__((ext_vector_type(4)));

__device__ __forceinline__ float wf(int j) {
    return sqrtf((float)(j + 1)) - sqrtf((float)j);
}
__device__ __forceinline__ float mcoef(int i, int k) {
    if (i == 0 || k > i) return 0.f;
    if (k == i) return 1.f;
    if (k == 0) return -wf(i - 1);
    int d = i - k;
    return wf(d) - wf(d - 1);
}
__device__ __forceinline__ unsigned short f2b(float f) {
    unsigned u = __float_as_uint(f);
    return (unsigned short)((u + 0x7FFFu + ((u >> 16) & 1u)) >> 16);
}
__device__ __forceinline__ float b2f(unsigned short h) {
    return __uint_as_float(((unsigned)h) << 16);
}

// ---- kernel 1: M as bf16 [512][512]
__global__ __launch_bounds__(256)
void build_m(unsigned short* __restrict__ M) {
    int i = blockIdx.x;
    for (int k = threadIdx.x; k < TT; k += 256)
        M[i * TT + k] = f2b(mcoef(i, k));
}

// ---- kernel 2: prepass. s = u - KD*lap - f1 (bf16 [t][px]), u_T = u^T (bf16 [px][t])
// block: 64 t x one y x 64 cols. grid 8160, XCD-chunk swizzled (y fastest per chunk).
__global__ __launch_bounds__(256)
void prepass(const float* __restrict__ uin, const float* __restrict__ f1,
             const float* __restrict__ lapk,
             unsigned short* __restrict__ uT, unsigned short* __restrict__ sB)
{
    __shared__ float          ls[64][3][67];   // u rows y-1..y+1, xx = 0..65
    __shared__ unsigned short us[64][72];      // bf16 center tile for transpose

    const int bid  = blockIdx.x;                         // 8160
    const int bid2 = (bid & 7) * 1020 + (bid >> 3);      // bijective chunk swizzle
    const int y    = 1 + bid2 % 255;
    const int rest = bid2 / 255;                         // 0..31
    const int xt   = rest & 3;
    const int tc   = rest >> 2;
    const int t0   = tc * 64;
    const int x0   = xt * 64;                            // col base (C-space)
    const int tid  = threadIdx.x;

    // stage u: 64 t x 3 rows x 66 xx   (x = x0 + xx)
    for (int e = tid; e < 64 * 3 * 66; e += 256) {
        int tt  = e / 198;
        int rem = e - tt * 198;
        int r   = rem / 66;
        int xx  = rem - r * 66;
        ls[tt][r][xx] = uin[(size_t)(t0 + tt) * IMG2 + (size_t)(y - 1 + r) * WW + (x0 + xx)];
    }
    __syncthreads();

    const float k00 = lapk[0], k01 = lapk[1], k02 = lapk[2];
    const float k10 = lapk[3], k11 = lapk[4], k12 = lapk[5];
    const float k20 = lapk[6], k21 = lapk[7], k22 = lapk[8];

    const int tt = tid >> 2;
    const int c0 = (tid & 3) * 16;
    unsigned short svals[16];
    const float* fb = f1 + (size_t)(t0 + tt) * HWSZ + (size_t)y * WW + (x0 + 1);
    #pragma unroll
    for (int j = 0; j < 16; ++j) {
        int c = c0 + j;
        bool pad = (x0 + c) == 255;
        float uc  = ls[tt][1][c + 1];
        float lap = k00 * ls[tt][0][c] + k01 * ls[tt][0][c + 1] + k02 * ls[tt][0][c + 2]
                  + k10 * ls[tt][1][c] + k11 * uc               + k12 * ls[tt][1][c + 2]
                  + k20 * ls[tt][2][c] + k21 * ls[tt][2][c + 1] + k22 * ls[tt][2][c + 2];
        float s = uc - KD * lap - fb[c];
        svals[j]     = pad ? 0 : f2b(s);
        us[tt][c]    = pad ? 0 : f2b(uc);
    }
    // write s (coalesced, 32 B per thread)
    size_t sbase = (size_t)(t0 + tt) * PX + (size_t)(y - 1) * 256 + x0 + c0;
    *(bf16x8*)(sB + sbase)     = *(bf16x8*)&svals[0];
    *(bf16x8*)(sB + sbase + 8) = *(bf16x8*)&svals[8];

    __syncthreads();
    // transposed u_T write: thread (c, tq) gathers 16 t's for pixel column c
    const int c  = tid >> 2;
    const int tq = tid & 3;
    unsigned short uv[16];
    #pragma unroll
    for (int j = 0; j < 16; ++j) uv[j] = us[16 * tq + j][c];
    size_t px = (size_t)(y - 1) * 256 + x0 + c;
    *(bf16x8*)(uT + px * TT + t0 + 16 * tq)     = *(bf16x8*)&uv[0];
    *(bf16x8*)(uT + px * TT + t0 + 16 * tq + 8) = *(bf16x8*)&uv[8];
}

// ---- kernel 3: MFMA GEMM + loss. block = 64 px x all 512 t, 8 balanced waves.
__global__ __launch_bounds__(512)
void mainker(const unsigned short* __restrict__ uT,
             const unsigned short* __restrict__ sB,
             const unsigned short* __restrict__ Mb,
             float* __restrict__ d_out)
{
    __shared__ unsigned short uS[64][512];   // 64 KB, XOR-swizzled 16B segments

    const int tid  = threadIdx.x;
    const int w    = tid >> 6;
    const int lane = tid & 63;
    const int lr   = lane & 15;
    const int lg   = lane >> 4;
    const int px0  = blockIdx.x * 64;

    // stage u tile once: wave w stages rows p = 8w..8w+7 (1 KB each)
    #pragma unroll
    for (int pr = 0; pr < 8; ++pr) {
        int p = 8 * w + pr;
        bf16x8 v = *(const bf16x8*)(uT + (size_t)(px0 + p) * TT + lane * 8);
        *(bf16x8*)(&uS[p][(lane ^ (p & 7)) * 8]) = v;
    }
    __syncthreads();

    float lsum = 0.f;
    #pragma unroll
    for (int half = 0; half < 2; ++half) {
        const int i0   = half ? 480 - 32 * w : 32 * w;
        const int nch  = half ? 16 - w : w + 1;        // k-chunks (balanced: 17 total)
        f32x4 acc[4][2];
        #pragma unroll
        for (int a = 0; a < 4; ++a) { acc[a][0] = (f32x4)0.f; acc[a][1] = (f32x4)0.f; }

        for (int kc = 0; kc < nch * 32; kc += 32) {
            bf16x8 b0 = *(const bf16x8*)(Mb + (size_t)(i0 + lr)      * TT + kc + 8 * lg);
            bf16x8 b1 = *(const bf16x8*)(Mb + (size_t)(i0 + 16 + lr) * TT + kc + 8 * lg);
            const int seg = (((kc >> 3) + lg) ^ (lr & 7)) * 8;
            #pragma unroll
            for (int mi = 0; mi < 4; ++mi) {
                bf16x8 a = *(const bf16x8*)(&uS[16 * mi + lr][seg]);
                acc[mi][0] = __builtin_amdgcn_mfma_f32_16x16x32_bf16(a, b0, acc[mi][0], 0, 0, 0);
                acc[mi][1] = __builtin_amdgcn_mfma_f32_16x16x32_bf16(a, b1, acc[mi][1], 0, 0, 0);
            }
        }
        // epilogue: res = SCALE*acc + s ; one 8-B s load per frag
        #pragma unroll
        for (int mi = 0; mi < 4; ++mi)
            #pragma unroll
            for (int nj = 0; nj < 2; ++nj) {
                int t = i0 + 16 * nj + lr;
                bf16x4 sv = *(const bf16x4*)(sB + (size_t)t * PX + px0 + 16 * mi + 4 * lg);
                f32x4 a = acc[mi][nj];
                #pragma unroll
                for (int r = 0; r < 4; ++r) {
                    float res = SCALE * a[r] + b2f((unsigned short)sv[r]);
                    lsum += res * res;
                }
            }
    }

    // reduce: wave shfl -> (reuse uS) -> one atomic per block
    #pragma unroll
    for (int off = 32; off > 0; off >>= 1)
        lsum += __shfl_down(lsum, off, 64);
    __syncthreads();                         // all waves done reading uS
    float* red = (float*)uS;
    if (lane == 0) red[w] = lsum;
    __syncthreads();
    if (tid == 0) {
        float tot = 0.f;
        #pragma unroll
        for (int q = 0; q < 8; ++q) tot += red[q];
        atomicAdd(d_out, tot * (1.0f / 33292800.0f));
    }
}

extern "C" void kernel_launch(void* const* d_in, const int* in_sizes, int n_in,
                              void* d_out, int out_size, void* d_ws, size_t ws_size,
                              hipStream_t stream)
{
    const float* uin  = (const float*)d_in[0];
    const float* f1   = (const float*)d_in[1];
    const float* lapk = (const float*)d_in[2];
    float* out = (float*)d_out;

    unsigned short* Mb = (unsigned short*)d_ws;                    // 512 KB
    unsigned short* uT = Mb + (size_t)TT * TT;                     // 66.8 MB  [px][t]
    unsigned short* sB = uT + (size_t)PX * TT;                     // 66.8 MB  [t][px]
    // total = 128 MiB exactly

    hipMemsetAsync(out, 0, sizeof(float), stream);
    build_m<<<dim3(TT), 256, 0, stream>>>(Mb);
    prepass<<<dim3(8160), 256, 0, stream>>>(uin, f1, lapk, uT, sB);
    mainker<<<dim3(PX / 64), 512, 0, stream>>>(uT, sB, Mb, out);
}

// Round 4
// 200.873 us; speedup vs baseline: 1.7122x; 1.7122x over previous
//
#include <hip/hip_runtime.h>

#define TT    512
#define WW    257
#define HWSZ  (WW*WW)          // 66049
#define IMG2  (2*HWSZ)         // time stride in `output` (2 channels)
#define PX    65280            // 255 rows * 256 padded cols (interior, col 255 = pad)
#define SCALE 3.5682482323055424f   // DT^-0.5 / gamma(1.5)
#define KD    163.84f               // KAPPA / DX^2
#define TCH   32                    // t-rows per prepass block

typedef short bf16x8 __attribute__((ext_vector_type(8)));
typedef short bf16x4 __attribute__((ext_vector_type(4)));
typedef float f32x4  __attribute__((ext_vector_type(4)));

__device__ __forceinline__ float wf(int j) {
    return sqrtf((float)(j + 1)) - sqrtf((float)j);
}
__device__ __forceinline__ float mcoef(int i, int k) {
    if (i == 0 || k > i) return 0.f;
    if (k == i) return 1.f;
    if (k == 0) return -wf(i - 1);
    int d = i - k;
    return wf(d) - wf(d - 1);
}
__device__ __forceinline__ unsigned short f2b(float f) {
    unsigned u = __float_as_uint(f);
    return (unsigned short)((u + 0x7FFFu + ((u >> 16) & 1u)) >> 16);
}
__device__ __forceinline__ float b2f(unsigned short h) {
    return __uint_as_float(((unsigned)h) << 16);
}

// ---- kernel 1: M as bf16 [512][512]
__global__ __launch_bounds__(256)
void build_m(unsigned short* __restrict__ M) {
    int i = blockIdx.x;
    for (int k = threadIdx.x; k < TT; k += 256)
        M[i * TT + k] = f2b(mcoef(i, k));
}

// ---- kernel 2: prepass v3. block = 32 t x one y. 256 thr = 4 waves.
// phase 1: per (t,y) row, register stencil -> s (global bf16) + u bf16 -> LDS
// phase 2: LDS transpose -> uT[px][t0..t0+31]
__global__ __launch_bounds__(256, 6)
void prepass(const float* __restrict__ uin, const float* __restrict__ f1,
             const float* __restrict__ lapk,
             unsigned short* __restrict__ uT, unsigned short* __restrict__ sB)
{
    __shared__ unsigned short uSm[TCH][260];

    const int bid  = blockIdx.x;                       // 4080 = 8 * 510
    const int bid2 = (bid & 7) * 510 + (bid >> 3);     // bijective XCD chunking
    const int y    = 1 + bid2 % 255;
    const int tch  = bid2 / 255;                       // 0..15
    const int t0   = tch * TCH;
    const int tid  = threadIdx.x;
    const int w    = tid >> 6;
    const int lane = tid & 63;

    const float k00 = lapk[0], k01 = lapk[1], k02 = lapk[2];
    const float k10 = lapk[3], k11 = lapk[4], k12 = lapk[5];
    const float k20 = lapk[6], k21 = lapk[7], k22 = lapk[8];

    // ---------- phase 1 ----------
    for (int it = 0; it < TCH / 4; ++it) {
        const int tt = w * (TCH / 4) + it;
        const int t  = t0 + tt;

        // stencil windows: win[r][i] = u[y-1+r][col 4*lane + i], i = 0..5
        float win[3][6];
        #pragma unroll
        for (int r = 0; r < 3; ++r) {
            size_t grow = (size_t)t * IMG2 + (size_t)(y - 1 + r) * WW;
            int    ar   = (int)(grow & 3);                       // wave-uniform
            const float* gp = uin + (grow - ar) + 4 * lane;      // 16B aligned
            f32x4 v = *(const f32x4*)gp;
            float f4 = __shfl(v[0], lane + 1, 64);
            float f5 = __shfl(v[1], lane + 1, 64);
            float f6 = __shfl(v[2], lane + 1, 64);
            float f7 = __shfl(v[3], lane + 1, 64);
            float f8 = __shfl(v[0], lane + 2, 64);
            if (lane >= 62) {                 // tail lanes: shfl wrapped, reload
                f32x4 tl = *(const f32x4*)(gp + 4);
                f4 = tl[0]; f5 = tl[1]; f6 = tl[2]; f7 = tl[3];
                f8 = gp[8];
            }
            float fa[9] = {v[0], v[1], v[2], v[3], f4, f5, f6, f7, f8};
            #pragma unroll
            for (int i = 0; i < 6; ++i) {
                float x0 = fa[i], x1 = fa[i + 1], x2 = fa[i + 2], x3 = fa[i + 3];
                win[r][i] = (ar == 0) ? x0 : (ar == 1) ? x1 : (ar == 2) ? x2 : x3;
            }
        }

        // f1 window: F[j] = f1[t][y][4*lane + 1 + j], j = 0..3
        float F[4];
        {
            size_t h1 = (size_t)t * HWSZ + (size_t)y * WW + 1;   // idx of x=1
            int    ah = (int)(h1 & 3);
            const float* gp = f1 + (h1 - ah) + 4 * lane;
            f32x4 v = *(const f32x4*)gp;
            float f4 = __shfl(v[0], lane + 1, 64);
            float f5 = __shfl(v[1], lane + 1, 64);
            float f6 = __shfl(v[2], lane + 1, 64);
            if (lane == 63) { f4 = gp[4]; f5 = gp[5]; f6 = gp[6]; }
            float fb[7] = {v[0], v[1], v[2], v[3], f4, f5, f6};
            #pragma unroll
            for (int j = 0; j < 4; ++j) {
                float x0 = fb[j], x1 = fb[j + 1], x2 = fb[j + 2], x3 = fb[j + 3];
                F[j] = (ah == 0) ? x0 : (ah == 1) ? x1 : (ah == 2) ? x2 : x3;
            }
        }

        // stencil + pack
        unsigned short ss[4], us[4];
        #pragma unroll
        for (int j = 0; j < 4; ++j) {
            int p = 4 * lane + j;             // px column 0..255 (255 = pad)
            float lap = k00 * win[0][j] + k01 * win[0][j + 1] + k02 * win[0][j + 2]
                      + k10 * win[1][j] + k11 * win[1][j + 1] + k12 * win[1][j + 2]
                      + k20 * win[2][j] + k21 * win[2][j + 1] + k22 * win[2][j + 2];
            float uc = win[1][j + 1];
            float s  = uc - KD * lap - F[j];
            bool pad = (p == 255);
            ss[j] = pad ? (unsigned short)0 : f2b(s);
            us[j] = pad ? (unsigned short)0 : f2b(uc);
        }
        // s -> global (8B aligned)
        ushort4 sv; sv.x = ss[0]; sv.y = ss[1]; sv.z = ss[2]; sv.w = ss[3];
        *(ushort4*)(sB + (size_t)t * PX + (size_t)(y - 1) * 256 + 4 * lane) = sv;
        // u -> LDS row (8B, rows padded to 260 entries = 520B, 8B-aligned)
        ushort4 uv; uv.x = us[0]; uv.y = us[1]; uv.z = us[2]; uv.w = us[3];
        *(ushort4*)(&uSm[tt][4 * lane]) = uv;
    }

    __syncthreads();

    // ---------- phase 2: transpose tile -> uT ----------
    const int c = tid;                       // pixel column 0..255
    unsigned short col[TCH];
    #pragma unroll
    for (int tt = 0; tt < TCH; ++tt) col[tt] = uSm[tt][c];

    unsigned short* dst = uT + ((size_t)(y - 1) * 256 + c) * TT + t0;
    #pragma unroll
    for (int q = 0; q < TCH / 8; ++q) {
        bf16x8 vq;
        #pragma unroll
        for (int e = 0; e < 8; ++e) vq[e] = (short)col[8 * q + e];
        *(bf16x8*)(dst + 8 * q) = vq;
    }
}

// ---- kernel 3: MFMA GEMM + loss. block = 64 px x all 512 t, 8 balanced waves.
__global__ __launch_bounds__(512)
void mainker(const unsigned short* __restrict__ uT,
             const unsigned short* __restrict__ sB,
             const unsigned short* __restrict__ Mb,
             float* __restrict__ d_out)
{
    __shared__ unsigned short uS[64][512];   // 64 KB, XOR-swizzled 16B segments

    const int tid  = threadIdx.x;
    const int w    = tid >> 6;
    const int lane = tid & 63;
    const int lr   = lane & 15;
    const int lg   = lane >> 4;
    const int px0  = blockIdx.x * 64;

    // stage u tile once: wave w stages rows p = 8w..8w+7 (1 KB each)
    #pragma unroll
    for (int pr = 0; pr < 8; ++pr) {
        int p = 8 * w + pr;
        bf16x8 v = *(const bf16x8*)(uT + (size_t)(px0 + p) * TT + lane * 8);
        *(bf16x8*)(&uS[p][(lane ^ (p & 7)) * 8]) = v;
    }
    __syncthreads();

    float lsum = 0.f;
    #pragma unroll
    for (int half = 0; half < 2; ++half) {
        const int i0   = half ? 480 - 32 * w : 32 * w;
        const int nch  = half ? 16 - w : w + 1;        // k-chunks (balanced: 17 total)
        f32x4 acc[4][2];
        #pragma unroll
        for (int a = 0; a < 4; ++a) { acc[a][0] = (f32x4)0.f; acc[a][1] = (f32x4)0.f; }

        for (int kc = 0; kc < nch * 32; kc += 32) {
            bf16x8 b0 = *(const bf16x8*)(Mb + (size_t)(i0 + lr)      * TT + kc + 8 * lg);
            bf16x8 b1 = *(const bf16x8*)(Mb + (size_t)(i0 + 16 + lr) * TT + kc + 8 * lg);
            const int seg = (((kc >> 3) + lg) ^ (lr & 7)) * 8;
            #pragma unroll
            for (int mi = 0; mi < 4; ++mi) {
                bf16x8 a = *(const bf16x8*)(&uS[16 * mi + lr][seg]);
                acc[mi][0] = __builtin_amdgcn_mfma_f32_16x16x32_bf16(a, b0, acc[mi][0], 0, 0, 0);
                acc[mi][1] = __builtin_amdgcn_mfma_f32_16x16x32_bf16(a, b1, acc[mi][1], 0, 0, 0);
            }
        }
        // epilogue: res = SCALE*acc + s ; one 8-B s load per frag
        #pragma unroll
        for (int mi = 0; mi < 4; ++mi)
            #pragma unroll
            for (int nj = 0; nj < 2; ++nj) {
                int t = i0 + 16 * nj + lr;
                bf16x4 sv = *(const bf16x4*)(sB + (size_t)t * PX + px0 + 16 * mi + 4 * lg);
                f32x4 a = acc[mi][nj];
                #pragma unroll
                for (int r = 0; r < 4; ++r) {
                    float res = SCALE * a[r] + b2f((unsigned short)sv[r]);
                    lsum += res * res;
                }
            }
    }

    // reduce: wave shfl -> (reuse uS) -> one atomic per block
    #pragma unroll
    for (int off = 32; off > 0; off >>= 1)
        lsum += __shfl_down(lsum, off, 64);
    __syncthreads();                         // all waves done reading uS
    float* red = (float*)uS;
    if (lane == 0) red[w] = lsum;
    __syncthreads();
    if (tid == 0) {
        float tot = 0.f;
        #pragma unroll
        for (int q = 0; q < 8; ++q) tot += red[q];
        atomicAdd(d_out, tot * (1.0f / 33292800.0f));
    }
}

extern "C" void kernel_launch(void* const* d_in, const int* in_sizes, int n_in,
                              void* d_out, int out_size, void* d_ws, size_t ws_size,
                              hipStream_t stream)
{
    const float* uin  = (const float*)d_in[0];
    const float* f1   = (const float*)d_in[1];
    const float* lapk = (const float*)d_in[2];
    float* out = (float*)d_out;

    unsigned short* Mb = (unsigned short*)d_ws;                    // 512 KB
    unsigned short* uT = Mb + (size_t)TT * TT;                     // 66.8 MB  [px][t]
    unsigned short* sB = uT + (size_t)PX * TT;                     // 66.8 MB  [t][px]

    hipMemsetAsync(out, 0, sizeof(float), stream);
    build_m<<<dim3(TT), 256, 0, stream>>>(Mb);
    prepass<<<dim3(4080), 256, 0, stream>>>(uin, f1, lapk, uT, sB);
    mainker<<<dim3(PX / 64), 512, 0, stream>>>(uT, sB, Mb, out);
}

// Round 5
// 178.368 us; speedup vs baseline: 1.9283x; 1.1262x over previous
//
#include <hip/hip_runtime.h>

#define TT    512
#define WW    257
#define HWSZ  (WW*WW)          // 66049
#define IMG2  (2*HWSZ)         // time stride in `output` (2 channels)
#define PX    65280            // 255 rows * 256 padded cols (interior, col 255 = pad)
#define SCALE 3.5682482323055424f   // DT^-0.5 / gamma(1.5)
#define KD    163.84f               // KAPPA / DX^2
#define TCH   32                    // t-rows per prepass block

typedef short bf16x8 __attribute__((ext_vector_type(8)));
typedef short bf16x4 __attribute__((ext_vector_type(4)));
typedef float f32x4  __attribute__((ext_vector_type(4)));
typedef float f32x4u __attribute__((ext_vector_type(4), aligned(4)));
typedef float f32x2u __attribute__((ext_vector_type(2), aligned(4)));

__device__ __forceinline__ float wf(int j) {
    return sqrtf((float)(j + 1)) - sqrtf((float)j);
}
__device__ __forceinline__ float mcoef(int i, int k) {
    if (i == 0 || k > i) return 0.f;
    if (k == i) return 1.f;
    if (k == 0) return -wf(i - 1);
    int d = i - k;
    return wf(d) - wf(d - 1);
}
__device__ __forceinline__ unsigned short f2b(float f) {
    unsigned u = __float_as_uint(f);
    return (unsigned short)((u + 0x7FFFu + ((u >> 16) & 1u)) >> 16);
}
__device__ __forceinline__ float b2f(unsigned short h) {
    return __uint_as_float(((unsigned)h) << 16);
}

// ---- kernel 1: M as bf16 [512][512]
__global__ __launch_bounds__(256)
void build_m(unsigned short* __restrict__ M) {
    int i = blockIdx.x;
    for (int k = threadIdx.x; k < TT; k += 256)
        M[i * TT + k] = f2b(mcoef(i, k));
}

// ---- kernel 2: prepass v4. block = 32 t x one y. 256 thr = 4 waves.
// Unaligned vector loads (4B-aligned dwordx4 is legal on gfx950); no shfl,
// no selects, no divergence. Stencil in registers -> s bf16 global + u bf16 LDS;
// phase 2 transposes the tile into uT[px][t].
__global__ __launch_bounds__(256, 6)
void prepass(const float* __restrict__ uin, const float* __restrict__ f1,
             const float* __restrict__ lapk,
             unsigned short* __restrict__ uT, unsigned short* __restrict__ sB)
{
    __shared__ unsigned short uSm[TCH][260];

    const int bid  = blockIdx.x;                       // 4080 = 8 * 510
    const int bid2 = (bid & 7) * 510 + (bid >> 3);     // bijective XCD chunking
    const int y    = 1 + bid2 % 255;
    const int tch  = bid2 / 255;                       // 0..15
    const int t0   = tch * TCH;
    const int tid  = threadIdx.x;
    const int w    = tid >> 6;
    const int lane = tid & 63;

    const float k00 = lapk[0], k01 = lapk[1], k02 = lapk[2];
    const float k10 = lapk[3], k11 = lapk[4], k12 = lapk[5];
    const float k20 = lapk[6], k21 = lapk[7], k22 = lapk[8];

    // ---------- phase 1 ----------
    #pragma unroll
    for (int it = 0; it < TCH / 4; ++it) {
        const int tt = w * (TCH / 4) + it;
        const int t  = t0 + tt;

        // windows: win[r][i] = u[t][y-1+r][4*lane + i], i = 0..5
        float win[3][6];
        const size_t base = (size_t)t * IMG2 + (size_t)(y - 1) * WW + 4 * lane;
        #pragma unroll
        for (int r = 0; r < 3; ++r) {
            const float* rp = uin + base + r * WW;
            f32x4u a = *(const f32x4u*)rp;
            f32x2u b = *(const f32x2u*)(rp + 4);   // lane63 tail: in-bounds, pad-only
            win[r][0] = a[0]; win[r][1] = a[1]; win[r][2] = a[2];
            win[r][3] = a[3]; win[r][4] = b[0]; win[r][5] = b[1];
        }
        // f1 window: F[j] = f1[t][y][4*lane + 1 + j]
        f32x4u F = *(const f32x4u*)(f1 + (size_t)t * HWSZ + (size_t)y * WW + 1 + 4 * lane);

        // stencil + pack
        unsigned short ss[4], us[4];
        #pragma unroll
        for (int j = 0; j < 4; ++j) {
            int p = 4 * lane + j;             // px column 0..255 (255 = pad)
            float lap = k00 * win[0][j] + k01 * win[0][j + 1] + k02 * win[0][j + 2]
                      + k10 * win[1][j] + k11 * win[1][j + 1] + k12 * win[1][j + 2]
                      + k20 * win[2][j] + k21 * win[2][j + 1] + k22 * win[2][j + 2];
            float uc = win[1][j + 1];
            float s  = uc - KD * lap - F[j];
            bool pad = (p == 255);
            ss[j] = pad ? (unsigned short)0 : f2b(s);
            us[j] = pad ? (unsigned short)0 : f2b(uc);
        }
        ushort4 sv; sv.x = ss[0]; sv.y = ss[1]; sv.z = ss[2]; sv.w = ss[3];
        *(ushort4*)(sB + (size_t)t * PX + (size_t)(y - 1) * 256 + 4 * lane) = sv;
        ushort4 uv; uv.x = us[0]; uv.y = us[1]; uv.z = us[2]; uv.w = us[3];
        *(ushort4*)(&uSm[tt][4 * lane]) = uv;
    }

    __syncthreads();

    // ---------- phase 2: transpose tile -> uT ----------
    const int c = tid;                       // pixel column 0..255
    unsigned short col[TCH];
    #pragma unroll
    for (int tt = 0; tt < TCH; ++tt) col[tt] = uSm[tt][c];

    unsigned short* dst = uT + ((size_t)(y - 1) * 256 + c) * TT + t0;
    #pragma unroll
    for (int q = 0; q < TCH / 8; ++q) {
        bf16x8 vq;
        #pragma unroll
        for (int e = 0; e < 8; ++e) vq[e] = (short)col[8 * q + e];
        *(bf16x8*)(dst + 8 * q) = vq;
    }
}

// ---- kernel 3: MFMA GEMM + loss. block = 64 px x all 512 t, 8 balanced waves.
__global__ __launch_bounds__(512)
void mainker(const unsigned short* __restrict__ uT,
             const unsigned short* __restrict__ sB,
             const unsigned short* __restrict__ Mb,
             float* __restrict__ d_out)
{
    __shared__ unsigned short uS[64][512];   // 64 KB, XOR-swizzled 16B segments

    const int tid  = threadIdx.x;
    const int w    = tid >> 6;
    const int lane = tid & 63;
    const int lr   = lane & 15;
    const int lg   = lane >> 4;
    const int px0  = blockIdx.x * 64;

    // stage u tile once: wave w stages rows p = 8w..8w+7 (1 KB each)
    #pragma unroll
    for (int pr = 0; pr < 8; ++pr) {
        int p = 8 * w + pr;
        bf16x8 v = *(const bf16x8*)(uT + (size_t)(px0 + p) * TT + lane * 8);
        *(bf16x8*)(&uS[p][(lane ^ (p & 7)) * 8]) = v;
    }
    __syncthreads();

    float lsum = 0.f;
    #pragma unroll
    for (int half = 0; half < 2; ++half) {
        const int i0   = half ? 480 - 32 * w : 32 * w;
        const int nch  = half ? 16 - w : w + 1;        // k-chunks (balanced: 17 total)
        f32x4 acc[4][2];
        #pragma unroll
        for (int a = 0; a < 4; ++a) { acc[a][0] = (f32x4)0.f; acc[a][1] = (f32x4)0.f; }

        for (int kc = 0; kc < nch * 32; kc += 32) {
            bf16x8 b0 = *(const bf16x8*)(Mb + (size_t)(i0 + lr)      * TT + kc + 8 * lg);
            bf16x8 b1 = *(const bf16x8*)(Mb + (size_t)(i0 + 16 + lr) * TT + kc + 8 * lg);
            const int seg = (((kc >> 3) + lg) ^ (lr & 7)) * 8;
            #pragma unroll
            for (int mi = 0; mi < 4; ++mi) {
                bf16x8 a = *(const bf16x8*)(&uS[16 * mi + lr][seg]);
                acc[mi][0] = __builtin_amdgcn_mfma_f32_16x16x32_bf16(a, b0, acc[mi][0], 0, 0, 0);
                acc[mi][1] = __builtin_amdgcn_mfma_f32_16x16x32_bf16(a, b1, acc[mi][1], 0, 0, 0);
            }
        }
        // epilogue: res = SCALE*acc + s ; one 8-B s load per frag
        #pragma unroll
        for (int mi = 0; mi < 4; ++mi)
            #pragma unroll
            for (int nj = 0; nj < 2; ++nj) {
                int t = i0 + 16 * nj + lr;
                bf16x4 sv = *(const bf16x4*)(sB + (size_t)t * PX + px0 + 16 * mi + 4 * lg);
                f32x4 a = acc[mi][nj];
                #pragma unroll
                for (int r = 0; r < 4; ++r) {
                    float res = SCALE * a[r] + b2f((unsigned short)sv[r]);
                    lsum += res * res;
                }
            }
    }

    // reduce: wave shfl -> (reuse uS) -> one atomic per block
    #pragma unroll
    for (int off = 32; off > 0; off >>= 1)
        lsum += __shfl_down(lsum, off, 64);
    __syncthreads();                         // all waves done reading uS
    float* red = (float*)uS;
    if (lane == 0) red[w] = lsum;
    __syncthreads();
    if (tid == 0) {
        float tot = 0.f;
        #pragma unroll
        for (int q = 0; q < 8; ++q) tot += red[q];
        atomicAdd(d_out, tot * (1.0f / 33292800.0f));
    }
}

extern "C" void kernel_launch(void* const* d_in, const int* in_sizes, int n_in,
                              void* d_out, int out_size, void* d_ws, size_t ws_size,
                              hipStream_t stream)
{
    const float* uin  = (const float*)d_in[0];
    const float* f1   = (const float*)d_in[1];
    const float* lapk = (const float*)d_in[2];
    float* out = (float*)d_out;

    unsigned short* Mb = (unsigned short*)d_ws;                    // 512 KB
    unsigned short* uT = Mb + (size_t)TT * TT;                     // 66.8 MB  [px][t]
    unsigned short* sB = uT + (size_t)PX * TT;                     // 66.8 MB  [t][px]

    hipMemsetAsync(out, 0, sizeof(float), stream);
    build_m<<<dim3(TT), 256, 0, stream>>>(Mb);
    prepass<<<dim3(4080), 256, 0, stream>>>(uin, f1, lapk, uT, sB);
    mainker<<<dim3(PX / 64), 512, 0, stream>>>(uT, sB, Mb, out);
}